// Round 15
// baseline (240.540 us; speedup 1.0000x reference)
//
#include <hip/hip_runtime.h>
#include <hip/hip_bf16.h>
#include <math.h>

#define D 128
#define H 4
#define NEG_SLOPE 0.2f
#define LN_EPS 1e-5f
#define LDA 136    // bf16 elems per LDS row: 272 B = 17*16B -> conflict-free b128
#define LDE 132    // f32 epilogue LDS row stride

using bf16x8 = __attribute__((ext_vector_type(8))) short;
using f32x4  = __attribute__((ext_vector_type(4))) float;

__device__ __forceinline__ float lrelu(float v) {
    return v > 0.f ? v : NEG_SLOPE * v;
}
__device__ __forceinline__ unsigned short bfb(float f) {
    __hip_bfloat16 h = __float2bfloat16(f);
    return *reinterpret_cast<unsigned short*>(&h);
}

// ---------- histogram + per-edge rank: rank[e] = old count of dst ----------
__global__ void k_rank(const int* __restrict__ ei, int* __restrict__ cnt,
                       int* __restrict__ rank, int E) {
    int e = blockIdx.x * blockDim.x + threadIdx.x;
    if (e >= E) return;
    rank[e] = atomicAdd(&cnt[ei[E + e]], 1);
}

// ---------- hierarchical exclusive scan of cnt[N] -> off[N+1] ----------
__global__ void k_scan_part(const int* __restrict__ cnt, int* __restrict__ off,
                            int* __restrict__ bsum, int N) {
    __shared__ int sm[256];
    int i = blockIdx.x * 256 + threadIdx.x;
    int v = (i < N) ? cnt[i] : 0;
    sm[threadIdx.x] = v;
    __syncthreads();
    #pragma unroll
    for (int o = 1; o < 256; o <<= 1) {
        int t = (threadIdx.x >= (unsigned)o) ? sm[threadIdx.x - o] : 0;
        __syncthreads();
        sm[threadIdx.x] += t;
        __syncthreads();
    }
    if (i < N) off[i] = sm[threadIdx.x];
    if (threadIdx.x == 255) bsum[blockIdx.x] = sm[255];
}

__global__ void k_scan_top(int* __restrict__ bsum, int* __restrict__ off,
                           int NB, int N) {
    __shared__ int sm[256];
    int v = (threadIdx.x < (unsigned)NB) ? bsum[threadIdx.x] : 0;
    sm[threadIdx.x] = v;
    __syncthreads();
    #pragma unroll
    for (int o = 1; o < 256; o <<= 1) {
        int t = (threadIdx.x >= (unsigned)o) ? sm[threadIdx.x - o] : 0;
        __syncthreads();
        sm[threadIdx.x] += t;
        __syncthreads();
    }
    if (threadIdx.x < (unsigned)NB) bsum[threadIdx.x] = sm[threadIdx.x] - v;
    if (threadIdx.x == 255) off[N] = sm[255];
}

__global__ void k_scan_add(const int* __restrict__ cnt, int* __restrict__ off,
                           const int* __restrict__ bsum, int N) {
    int i = blockIdx.x * 256 + threadIdx.x;
    if (i < N) off[i] = off[i] - cnt[i] + bsum[blockIdx.x];
}

// ---------- CSR fill, ATOMIC-FREE. adj[slot]=src (4B); xp[slot]=x[e] ----------
__global__ void k_fill(const int* __restrict__ ei, const int* __restrict__ off,
                       const int* __restrict__ rank, const float* __restrict__ x,
                       int* __restrict__ adj, float* __restrict__ xp, int E) {
    int e = blockIdx.x * blockDim.x + threadIdx.x;
    if (e >= E) return;
    int dst = ei[E + e];
    int slot = off[dst] + rank[e];
    adj[slot] = ei[e];
    const float* xr = x + (size_t)e * 3;
    float* d = xp + (size_t)slot * 3;
    d[0] = xr[0]; d[1] = xr[1]; d[2] = xr[2];
}

// ---------- weight prep: Wt[w][n][k] = bf16(W_w[k][n]) (transposed) ----------
__global__ __launch_bounds__(256) void k_wprep(
        const float* __restrict__ Wn, const float* __restrict__ lw,
        unsigned short* __restrict__ Wt) {
    __shared__ float Wf[32][132];
    int b = blockIdx.x, w = b >> 2, p = b & 3;
    const float* src = (w == 0) ? (Wn + (size_t)p * 32 * D)
                                : (lw + (size_t)(w - 1) * D * D + (size_t)p * 32 * D);
    int tid = threadIdx.x;
    #pragma unroll
    for (int j = 0; j < 4; j++) {
        int i = tid + j * 256;
        int r = i >> 5, q = i & 31;
        float4 v = reinterpret_cast<const float4*>(src)[i];
        *reinterpret_cast<float4*>(&Wf[r][q * 4]) = v;
    }
    __syncthreads();
    int n = tid & 127, ks = (tid >> 7) * 16;
    unsigned short t16[16];
    #pragma unroll
    for (int j = 0; j < 16; j++) t16[j] = bfb(Wf[ks + j][n]);
    unsigned short* dst = Wt + ((size_t)w * D + n) * D + p * 32 + ks;
    *reinterpret_cast<uint4*>(dst) = *reinterpret_cast<uint4*>(t16);
    *reinterpret_cast<uint4*>(dst + 8) = *reinterpret_cast<uint4*>(t16 + 8);
}

// ---------- MFMA GEMM: C[N,128] = bf16(A[N,128]) @ bf16(W[128,128]) ----------
// 64 rows/block, 512 threads = 8 waves: wave w -> rows (w&3)*16, col-tiles
// (w>>2)*4..+3.
// MODE 1: A = hb (bf16 copy of h), bf16 out + fused attention dots.
// MODE 2: A synthesized from scatter-mean (contiguous xp), f32 out + bias,
//         also writes hb.
template <int MODE>
__global__ __launch_bounds__(512) void k_gemm(
        const unsigned short* __restrict__ hb_in,
        const unsigned short* __restrict__ Wt,
        const float* __restrict__ bias, float* __restrict__ C,
        unsigned short* __restrict__ hb_out,
        __hip_bfloat16* __restrict__ xhb, float* __restrict__ a_s,
        float* __restrict__ a_d, const float* __restrict__ att_s,
        const float* __restrict__ att_d,
        const float* __restrict__ xp, const int* __restrict__ off,
        const float* __restrict__ W_edge, const float* __restrict__ b_edge,
        int N) {
    __shared__ __align__(16) unsigned short AsB[64 * LDA];   // 17.4 KB
    __shared__ __align__(16) unsigned short WtB[128 * LDA];  // 34.8 KB (f32 [64][LDE] in epilogue)
    int tid = threadIdx.x;
    int n0 = blockIdx.x * 64;

    // stage Wt (pre-transposed bf16 [128][128]) -> LDS [128][LDA]
    #pragma unroll
    for (int j = 0; j < 4; j++) {
        int ch = tid + j * 512;
        int r = ch >> 4, c = ch & 15;
        uint4 v = *reinterpret_cast<const uint4*>(Wt + (size_t)r * D + c * 8);
        *reinterpret_cast<uint4*>(&WtB[r * LDA + c * 8]) = v;
    }

    if (MODE == 2) {
        __shared__ float rowf[64][4];
        {
            int r = tid >> 3, t8v = tid & 7;
            int n = n0 + r;
            float s0 = 0.f, s1 = 0.f, s2 = 0.f;
            int degv = 0;
            if (n < N) {
                int beg = off[n], end = off[n + 1];
                degv = end - beg;
                for (int p = beg + t8v; p < end; p += 8) {
                    const float* xr = xp + (size_t)p * 3;
                    s0 += xr[0]; s1 += xr[1]; s2 += xr[2];
                }
            }
            #pragma unroll
            for (int o = 1; o < 8; o <<= 1) {
                s0 += __shfl_xor(s0, o);
                s1 += __shfl_xor(s1, o);
                s2 += __shfl_xor(s2, o);
            }
            if (t8v == 0)
                *reinterpret_cast<float4*>(rowf[r]) =
                    make_float4(s0, s1, s2, (float)degv);
        }
        __syncthreads();
        #pragma unroll
        for (int j = 0; j < 2; j++) {
            int ch = tid + j * 512;
            int r = ch >> 4, c = ch & 15;
            float4 rv = *reinterpret_cast<float4*>(rowf[r]);
            float cn = rv.w, rc = 1.f / fmaxf(cn, 1.f);
            int d0 = c * 8;
            unsigned short t8[8];
            #pragma unroll
            for (int q = 0; q < 2; q++) {
                float4 we0 = *reinterpret_cast<const float4*>(W_edge + d0 + q * 4);
                float4 we1 = *reinterpret_cast<const float4*>(W_edge + D + d0 + q * 4);
                float4 we2 = *reinterpret_cast<const float4*>(W_edge + 2 * D + d0 + q * 4);
                float4 be  = *reinterpret_cast<const float4*>(b_edge + d0 + q * 4);
                t8[q * 4 + 0] = bfb((rv.x * we0.x + rv.y * we1.x + rv.z * we2.x + cn * be.x) * rc);
                t8[q * 4 + 1] = bfb((rv.x * we0.y + rv.y * we1.y + rv.z * we2.y + cn * be.y) * rc);
                t8[q * 4 + 2] = bfb((rv.x * we0.z + rv.y * we1.z + rv.z * we2.z + cn * be.z) * rc);
                t8[q * 4 + 3] = bfb((rv.x * we0.w + rv.y * we1.w + rv.z * we2.w + cn * be.w) * rc);
            }
            *reinterpret_cast<uint4*>(&AsB[r * LDA + c * 8]) =
                *reinterpret_cast<uint4*>(t8);
        }
    } else {
        // A staging = pure 16B copies from hb (bf16 copy of h)
        #pragma unroll
        for (int j = 0; j < 2; j++) {
            int ch = tid + j * 512;
            int r = ch >> 4, c = ch & 15;
            int n = n0 + r;
            uint4 v = make_uint4(0, 0, 0, 0);
            if (n < N)
                v = *reinterpret_cast<const uint4*>(hb_in + (size_t)n * D + c * 8);
            *reinterpret_cast<uint4*>(&AsB[r * LDA + c * 8]) = v;
        }
    }
    __syncthreads();

    // 8 waves: wave w -> rows (w&3)*16, col-tiles (w>>2)*4 .. +3
    int lane = tid & 63, wv = tid >> 6;
    int wr = wv & 3, wc = wv >> 2;
    int lrow = lane & 15, lk = lane >> 4;
    f32x4 acc[4];
    #pragma unroll
    for (int ct = 0; ct < 4; ct++) acc[ct] = (f32x4){0.f, 0.f, 0.f, 0.f};
    int arow = wr * 16 + lrow;
    #pragma unroll
    for (int ks = 0; ks < 4; ks++) {
        bf16x8 af = *reinterpret_cast<const bf16x8*>(
            &AsB[arow * LDA + ks * 32 + lk * 8]);
        #pragma unroll
        for (int ct = 0; ct < 4; ct++) {
            bf16x8 bfr = *reinterpret_cast<const bf16x8*>(
                &WtB[((wc * 4 + ct) * 16 + lrow) * LDA + ks * 32 + lk * 8]);
            acc[ct] = __builtin_amdgcn_mfma_f32_16x16x32_bf16(af, bfr, acc[ct], 0, 0, 0);
        }
    }
    __syncthreads();   // all reads of AsB/WtB done; reuse WtB as f32 staging

    float* Ef = reinterpret_cast<float*>(WtB);
    #pragma unroll
    for (int ct = 0; ct < 4; ct++)
        #pragma unroll
        for (int j = 0; j < 4; j++)
            Ef[(wr * 16 + lk * 4 + j) * LDE + (wc * 4 + ct) * 16 + lrow] = acc[ct][j];
    __syncthreads();

    // epilogue: 512 threads, each handles 2 rows x 8 cols
    int tx = tid & 15, ty = tid >> 4;
    int c0 = tx * 8, r0 = ty * 2;
    float o[2][8];
    #pragma unroll
    for (int r = 0; r < 2; r++) {
        float4 v0 = *reinterpret_cast<const float4*>(&Ef[(r0 + r) * LDE + c0]);
        float4 v1 = *reinterpret_cast<const float4*>(&Ef[(r0 + r) * LDE + c0 + 4]);
        o[r][0] = v0.x; o[r][1] = v0.y; o[r][2] = v0.z; o[r][3] = v0.w;
        o[r][4] = v1.x; o[r][5] = v1.y; o[r][6] = v1.z; o[r][7] = v1.w;
    }

    if (MODE == 2) {
        float b[8];
        #pragma unroll
        for (int c = 0; c < 8; c++) b[c] = bias[c0 + c];
        #pragma unroll
        for (int r = 0; r < 2; r++) {
            int n = n0 + r0 + r;
            if (n >= N) continue;
            float oo[8];
            #pragma unroll
            for (int c = 0; c < 8; c++) oo[c] = o[r][c] + b[c];
            float4 o0 = make_float4(oo[0], oo[1], oo[2], oo[3]);
            float4 o1 = make_float4(oo[4], oo[5], oo[6], oo[7]);
            reinterpret_cast<float4*>(C)[(size_t)n * 32 + tx * 2] = o0;
            reinterpret_cast<float4*>(C)[(size_t)n * 32 + tx * 2 + 1] = o1;
            union { uint4 v; unsigned short s[8]; } pk;
            #pragma unroll
            for (int c = 0; c < 8; c++) pk.s[c] = bfb(oo[c]);
            *reinterpret_cast<uint4*>(hb_out + (size_t)n * D + c0) = pk.v;
        }
    } else {
        float ats[8], atd[8];
        #pragma unroll
        for (int c = 0; c < 8; c++) { ats[c] = att_s[c0 + c]; atd[c] = att_d[c0 + c]; }
        #pragma unroll
        for (int r = 0; r < 2; r++) {
            int n = n0 + r0 + r;
            union { uint4 v; unsigned short s[8]; } pk;
            #pragma unroll
            for (int c = 0; c < 8; c++) pk.s[c] = bfb(o[r][c]);
            float ps = 0.f, pd = 0.f;
            #pragma unroll
            for (int c = 0; c < 8; c++) { ps += o[r][c] * ats[c]; pd += o[r][c] * atd[c]; }
            ps += __shfl_xor(ps, 1); ps += __shfl_xor(ps, 2);
            pd += __shfl_xor(pd, 1); pd += __shfl_xor(pd, 2);
            if (n < N) {
                *reinterpret_cast<uint4*>(xhb + (size_t)n * D + c0) = pk.v;
                if ((tx & 3) == 0) {
                    a_s[n * H + (tx >> 2)] = ps;
                    a_d[n * H + (tx >> 2)] = pd;
                }
            }
        }
    }
}

// ---------- fused GAT aggregate + bias + LN (+ReLU) + residual ----------
// One wave per node, 4 nodes per 256-thread block. SINGLE PASS:
// no segment-max (lrelu-bounded logits -> exp safe in f32), no LDS.
// Also maintains hb (bf16 copy of h) for the next layer's GEMM staging.
__global__ __launch_bounds__(256) void k_gat5(
        const __hip_bfloat16* __restrict__ xhb, const int* __restrict__ off,
        const int* __restrict__ adj, const float* __restrict__ a_s,
        const float* __restrict__ a_d, const float* __restrict__ bias,
        const float* __restrict__ g, const float* __restrict__ bln,
        float* __restrict__ h, unsigned short* __restrict__ hb,
        int N, int do_relu) {
    int wid = threadIdx.x >> 6;
    int lane = threadIdx.x & 63;
    int n = blockIdx.x * 4 + wid;
    if (n >= N) return;

    int cl = lane & 15;             // channel group: c0 = 8*cl
    int sub = lane >> 4;            // edge sub-slot (4 edges in flight)
    int hbd = cl >> 2;              // head of this lane's channels
    int c0 = cl * 8;

    int beg = off[n], end = off[n + 1];
    int deg = end - beg;
    int items = deg + 1;            // + self loop
    int itp = (items + 3) & ~3;

    float adA = a_d[n * H + hbd];
    float den = 0.f;
    float acc[8];
    #pragma unroll
    for (int c = 0; c < 8; c++) acc[c] = 0.f;

    #pragma unroll 4
    for (int pp = sub; pp < itp; pp += 4) {
        int s = (pp < deg) ? adj[beg + pp] : n;
        float av = a_s[(size_t)s * H + hbd];
        uint4 u = *reinterpret_cast<const uint4*>(xhb + (size_t)s * D + c0);
        float e = lrelu(av + adA);
        float wv = (pp < items) ? __expf(e) : 0.f;
        den += wv;
        float f;
        f = __uint_as_float(u.x << 16);         acc[0] += wv * f;
        f = __uint_as_float(u.x & 0xffff0000u); acc[1] += wv * f;
        f = __uint_as_float(u.y << 16);         acc[2] += wv * f;
        f = __uint_as_float(u.y & 0xffff0000u); acc[3] += wv * f;
        f = __uint_as_float(u.z << 16);         acc[4] += wv * f;
        f = __uint_as_float(u.z & 0xffff0000u); acc[5] += wv * f;
        f = __uint_as_float(u.w << 16);         acc[6] += wv * f;
        f = __uint_as_float(u.w & 0xffff0000u); acc[7] += wv * f;
    }

    #pragma unroll
    for (int c = 0; c < 8; c++) {
        acc[c] += __shfl_xor(acc[c], 16);
        acc[c] += __shfl_xor(acc[c], 32);
    }
    den += __shfl_xor(den, 16);
    den += __shfl_xor(den, 32);
    float rden = 1.0f / den;

    float4 b0 = *reinterpret_cast<const float4*>(bias + c0);
    float4 b1 = *reinterpret_cast<const float4*>(bias + c0 + 4);
    float o[8];
    o[0] = acc[0] * rden + b0.x; o[1] = acc[1] * rden + b0.y;
    o[2] = acc[2] * rden + b0.z; o[3] = acc[3] * rden + b0.w;
    o[4] = acc[4] * rden + b1.x; o[5] = acc[5] * rden + b1.y;
    o[6] = acc[6] * rden + b1.z; o[7] = acc[7] * rden + b1.w;

    float s1 = 0.f;
    #pragma unroll
    for (int c = 0; c < 8; c++) s1 += o[c];
    #pragma unroll
    for (int os = 1; os < 64; os <<= 1) s1 += __shfl_xor(s1, os);
    float mu = s1 * (1.0f / 512.0f);
    float s2 = 0.f;
    #pragma unroll
    for (int c = 0; c < 8; c++) { float dv = o[c] - mu; s2 += dv * dv; }
    #pragma unroll
    for (int os = 1; os < 64; os <<= 1) s2 += __shfl_xor(s2, os);
    float inv = rsqrtf(s2 * (1.0f / 512.0f) + LN_EPS);

    if (sub == 0) {
        float4 g0 = *reinterpret_cast<const float4*>(g + c0);
        float4 g1 = *reinterpret_cast<const float4*>(g + c0 + 4);
        float4 l0 = *reinterpret_cast<const float4*>(bln + c0);
        float4 l1 = *reinterpret_cast<const float4*>(bln + c0 + 4);
        float y[8];
        y[0] = (o[0] - mu) * inv * g0.x + l0.x;
        y[1] = (o[1] - mu) * inv * g0.y + l0.y;
        y[2] = (o[2] - mu) * inv * g0.z + l0.z;
        y[3] = (o[3] - mu) * inv * g0.w + l0.w;
        y[4] = (o[4] - mu) * inv * g1.x + l1.x;
        y[5] = (o[5] - mu) * inv * g1.y + l1.y;
        y[6] = (o[6] - mu) * inv * g1.z + l1.z;
        y[7] = (o[7] - mu) * inv * g1.w + l1.w;
        if (do_relu) {
            #pragma unroll
            for (int c = 0; c < 8; c++) y[c] = fmaxf(y[c], 0.f);
        }
        float4 h0 = *reinterpret_cast<float4*>(h + (size_t)n * D + c0);
        float4 h1 = *reinterpret_cast<float4*>(h + (size_t)n * D + c0 + 4);
        h0.x += y[0]; h0.y += y[1]; h0.z += y[2]; h0.w += y[3];
        h1.x += y[4]; h1.y += y[5]; h1.z += y[6]; h1.w += y[7];
        *reinterpret_cast<float4*>(h + (size_t)n * D + c0) = h0;
        *reinterpret_cast<float4*>(h + (size_t)n * D + c0 + 4) = h1;
        union { uint4 v; unsigned short s[8]; } pk;
        pk.s[0] = bfb(h0.x); pk.s[1] = bfb(h0.y);
        pk.s[2] = bfb(h0.z); pk.s[3] = bfb(h0.w);
        pk.s[4] = bfb(h1.x); pk.s[5] = bfb(h1.y);
        pk.s[6] = bfb(h1.z); pk.s[7] = bfb(h1.w);
        *reinterpret_cast<uint4*>(hb + (size_t)n * D + c0) = pk.v;
    }
}

extern "C" void kernel_launch(void* const* d_in, const int* in_sizes, int n_in,
                              void* d_out, int out_size, void* d_ws, size_t ws_size,
                              hipStream_t stream) {
    const float* x       = (const float*)d_in[0];
    const int*   ei      = (const int*)  d_in[1];
    const float* W_edge  = (const float*)d_in[2];
    const float* b_edge  = (const float*)d_in[3];
    const float* W_node  = (const float*)d_in[4];
    const float* b_node  = (const float*)d_in[5];
    const float* lin_w   = (const float*)d_in[6];
    const float* att_src = (const float*)d_in[7];
    const float* att_dst = (const float*)d_in[8];
    const float* gat_b   = (const float*)d_in[9];
    const float* ln_g    = (const float*)d_in[10];
    const float* ln_b    = (const float*)d_in[11];

    int N = out_size / D;
    int E = in_sizes[1] / 2;
    int NB = (N + 255) / 256;

    char* w = (char*)d_ws;
    auto carve = [&](size_t bytes) {
        void* p = (void*)w;
        w += (bytes + 255) & ~(size_t)255;
        return p;
    };
    int*   cnt  = (int*)  carve((size_t)N * 4);
    int*   off  = (int*)  carve((size_t)(N + 1) * 4);
    int*   rank = (int*)  carve((size_t)E * 4);
    int*   adj  = (int*)  carve((size_t)E * 4);
    float* xp   = (float*)carve((size_t)E * 3 * 4);
    int*   bsum = (int*)  carve((size_t)NB * 4);
    float* tmp  = (float*)carve((size_t)N * D * 4);   // [xhb bf16 | hb bf16]
    float* a_s  = (float*)carve((size_t)N * H * 4);
    float* a_d  = (float*)carve((size_t)N * H * 4);
    unsigned short* Wt = (unsigned short*)carve((size_t)4 * D * D * 2);
    __hip_bfloat16* xhb = (__hip_bfloat16*)tmp;
    unsigned short* hb  = (unsigned short*)((char*)tmp + (size_t)N * D * 2);

    float* h = (float*)d_out;

    hipMemsetAsync(cnt, 0, (size_t)N * 4, stream);

    int tb = 256;
    k_wprep<<<16, 256, 0, stream>>>(W_node, lin_w, Wt);
    k_rank<<<(E + tb - 1) / tb, tb, 0, stream>>>(ei, cnt, rank, E);
    k_scan_part<<<NB, 256, 0, stream>>>(cnt, off, bsum, N);
    k_scan_top<<<1, 256, 0, stream>>>(bsum, off, NB, N);
    k_scan_add<<<NB, 256, 0, stream>>>(cnt, off, bsum, N);
    k_fill<<<(E + tb - 1) / tb, tb, 0, stream>>>(ei, off, rank, x, adj, xp, E);
    k_gemm<2><<<(N + 63) / 64, 512, 0, stream>>>(
        nullptr, Wt, b_node, h, hb, nullptr, nullptr, nullptr, nullptr, nullptr,
        xp, off, W_edge, b_edge, N);

    for (int i = 0; i < 3; i++) {
        k_gemm<1><<<(N + 63) / 64, 512, 0, stream>>>(
            hb, Wt + (size_t)(i + 1) * D * D, nullptr, nullptr, nullptr,
            xhb, a_s, a_d, att_src + i * D, att_dst + i * D,
            nullptr, nullptr, nullptr, nullptr, N);
        k_gat5<<<(N + 3) / 4, 256, 0, stream>>>(
            xhb, off, adj, a_s, a_d,
            gat_b + i * D, ln_g + i * D, ln_b + i * D,
            h, hb, N, (i < 2) ? 1 : 0);
    }
}

// Round 16
// 237.948 us; speedup vs baseline: 1.0109x; 1.0109x over previous
//
#include <hip/hip_runtime.h>
#include <hip/hip_bf16.h>
#include <math.h>

#define D 128
#define H 4
#define NEG_SLOPE 0.2f
#define LN_EPS 1e-5f
#define LDA 136    // bf16 elems per LDS row: 272 B = 17*16B -> conflict-free b128
#define LDE 132    // f32 epilogue LDS row stride

using bf16x8 = __attribute__((ext_vector_type(8))) short;
using f32x4  = __attribute__((ext_vector_type(4))) float;

__device__ __forceinline__ float lrelu(float v) {
    return v > 0.f ? v : NEG_SLOPE * v;
}
__device__ __forceinline__ unsigned short bfb(float f) {
    __hip_bfloat16 h = __float2bfloat16(f);
    return *reinterpret_cast<unsigned short*>(&h);
}

// ---------- histogram + per-edge rank: rank[e] = old count of dst ----------
__global__ void k_rank(const int* __restrict__ ei, int* __restrict__ cnt,
                       int* __restrict__ rank, int E) {
    int e = blockIdx.x * blockDim.x + threadIdx.x;
    if (e >= E) return;
    rank[e] = atomicAdd(&cnt[ei[E + e]], 1);
}

// ---------- hierarchical exclusive scan of cnt[N] -> off[N+1] ----------
__global__ void k_scan_part(const int* __restrict__ cnt, int* __restrict__ off,
                            int* __restrict__ bsum, int N) {
    __shared__ int sm[256];
    int i = blockIdx.x * 256 + threadIdx.x;
    int v = (i < N) ? cnt[i] : 0;
    sm[threadIdx.x] = v;
    __syncthreads();
    #pragma unroll
    for (int o = 1; o < 256; o <<= 1) {
        int t = (threadIdx.x >= (unsigned)o) ? sm[threadIdx.x - o] : 0;
        __syncthreads();
        sm[threadIdx.x] += t;
        __syncthreads();
    }
    if (i < N) off[i] = sm[threadIdx.x];
    if (threadIdx.x == 255) bsum[blockIdx.x] = sm[255];
}

__global__ void k_scan_top(int* __restrict__ bsum, int* __restrict__ off,
                           int NB, int N) {
    __shared__ int sm[256];
    int v = (threadIdx.x < (unsigned)NB) ? bsum[threadIdx.x] : 0;
    sm[threadIdx.x] = v;
    __syncthreads();
    #pragma unroll
    for (int o = 1; o < 256; o <<= 1) {
        int t = (threadIdx.x >= (unsigned)o) ? sm[threadIdx.x - o] : 0;
        __syncthreads();
        sm[threadIdx.x] += t;
        __syncthreads();
    }
    if (threadIdx.x < (unsigned)NB) bsum[threadIdx.x] = sm[threadIdx.x] - v;
    if (threadIdx.x == 255) off[N] = sm[255];
}

__global__ void k_scan_add(const int* __restrict__ cnt, int* __restrict__ off,
                           const int* __restrict__ bsum, int N) {
    int i = blockIdx.x * 256 + threadIdx.x;
    if (i < N) off[i] = off[i] - cnt[i] + bsum[blockIdx.x];
}

// ---------- CSR fill, ATOMIC-FREE: slot = off[dst] + rank[e] ----------
__global__ void k_fill(const int* __restrict__ ei, const int* __restrict__ off,
                       const int* __restrict__ rank, int2* __restrict__ adj2, int E) {
    int e = blockIdx.x * blockDim.x + threadIdx.x;
    if (e >= E) return;
    int dst = ei[E + e];
    int slot = off[dst] + rank[e];
    adj2[slot] = make_int2(ei[e], e);
}

// ---------- weight prep: Wt[w][n][k] = bf16(W_w[k][n]) (transposed) ----------
__global__ __launch_bounds__(256) void k_wprep(
        const float* __restrict__ Wn, const float* __restrict__ lw,
        unsigned short* __restrict__ Wt) {
    __shared__ float Wf[32][132];
    int b = blockIdx.x, w = b >> 2, p = b & 3;
    const float* src = (w == 0) ? (Wn + (size_t)p * 32 * D)
                                : (lw + (size_t)(w - 1) * D * D + (size_t)p * 32 * D);
    int tid = threadIdx.x;
    #pragma unroll
    for (int j = 0; j < 4; j++) {
        int i = tid + j * 256;
        int r = i >> 5, q = i & 31;
        float4 v = reinterpret_cast<const float4*>(src)[i];
        *reinterpret_cast<float4*>(&Wf[r][q * 4]) = v;
    }
    __syncthreads();
    int n = tid & 127, ks = (tid >> 7) * 16;
    unsigned short t16[16];
    #pragma unroll
    for (int j = 0; j < 16; j++) t16[j] = bfb(Wf[ks + j][n]);
    unsigned short* dst = Wt + ((size_t)w * D + n) * D + p * 32 + ks;
    *reinterpret_cast<uint4*>(dst) = *reinterpret_cast<uint4*>(t16);
    *reinterpret_cast<uint4*>(dst + 8) = *reinterpret_cast<uint4*>(t16 + 8);
}

// ---------- MFMA GEMM: C[N,128] = bf16(A[N,128]) @ bf16(W[128,128]) ----------
// 64 rows/block, 512 threads = 8 waves: wave w -> rows (w&3)*16, col-tiles
// (w>>2)*4..+3.
// MODE 1: A explicit (h), bf16 out + fused attention dots.
// MODE 2: A synthesized from scatter-mean, f32 out + bias.
template <int MODE>
__global__ __launch_bounds__(512) void k_gemm(
        const float* __restrict__ A, const unsigned short* __restrict__ Wt,
        const float* __restrict__ bias, float* __restrict__ C,
        __hip_bfloat16* __restrict__ xhb, float* __restrict__ a_s,
        float* __restrict__ a_d, const float* __restrict__ att_s,
        const float* __restrict__ att_d,
        const float* __restrict__ x, const int2* __restrict__ adj2,
        const int* __restrict__ off,
        const float* __restrict__ W_edge, const float* __restrict__ b_edge,
        int N) {
    __shared__ __align__(16) unsigned short AsB[64 * LDA];   // 17.4 KB
    __shared__ __align__(16) unsigned short WtB[128 * LDA];  // 34.8 KB (f32 [64][LDE] in epilogue)
    int tid = threadIdx.x;
    int n0 = blockIdx.x * 64;

    // stage Wt (pre-transposed bf16 [128][128]) -> LDS [128][LDA]
    #pragma unroll
    for (int j = 0; j < 4; j++) {
        int ch = tid + j * 512;
        int r = ch >> 4, c = ch & 15;
        uint4 v = *reinterpret_cast<const uint4*>(Wt + (size_t)r * D + c * 8);
        *reinterpret_cast<uint4*>(&WtB[r * LDA + c * 8]) = v;
    }

    if (MODE == 2) {
        __shared__ float rowf[64][4];
        {
            int r = tid >> 3, t8v = tid & 7;
            int n = n0 + r;
            float s0 = 0.f, s1 = 0.f, s2 = 0.f;
            int degv = 0;
            if (n < N) {
                int beg = off[n], end = off[n + 1];
                degv = end - beg;
                for (int p = beg + t8v; p < end; p += 8) {
                    const float* xr = x + (size_t)adj2[p].y * 3;
                    s0 += xr[0]; s1 += xr[1]; s2 += xr[2];
                }
            }
            #pragma unroll
            for (int o = 1; o < 8; o <<= 1) {
                s0 += __shfl_xor(s0, o);
                s1 += __shfl_xor(s1, o);
                s2 += __shfl_xor(s2, o);
            }
            if (t8v == 0)
                *reinterpret_cast<float4*>(rowf[r]) =
                    make_float4(s0, s1, s2, (float)degv);
        }
        __syncthreads();
        #pragma unroll
        for (int j = 0; j < 2; j++) {
            int ch = tid + j * 512;
            int r = ch >> 4, c = ch & 15;
            float4 rv = *reinterpret_cast<float4*>(rowf[r]);
            float cn = rv.w, rc = 1.f / fmaxf(cn, 1.f);
            int d0 = c * 8;
            unsigned short t8[8];
            #pragma unroll
            for (int q = 0; q < 2; q++) {
                float4 we0 = *reinterpret_cast<const float4*>(W_edge + d0 + q * 4);
                float4 we1 = *reinterpret_cast<const float4*>(W_edge + D + d0 + q * 4);
                float4 we2 = *reinterpret_cast<const float4*>(W_edge + 2 * D + d0 + q * 4);
                float4 be  = *reinterpret_cast<const float4*>(b_edge + d0 + q * 4);
                t8[q * 4 + 0] = bfb((rv.x * we0.x + rv.y * we1.x + rv.z * we2.x + cn * be.x) * rc);
                t8[q * 4 + 1] = bfb((rv.x * we0.y + rv.y * we1.y + rv.z * we2.y + cn * be.y) * rc);
                t8[q * 4 + 2] = bfb((rv.x * we0.z + rv.y * we1.z + rv.z * we2.z + cn * be.z) * rc);
                t8[q * 4 + 3] = bfb((rv.x * we0.w + rv.y * we1.w + rv.z * we2.w + cn * be.w) * rc);
            }
            *reinterpret_cast<uint4*>(&AsB[r * LDA + c * 8]) =
                *reinterpret_cast<uint4*>(t8);
        }
    } else {
        #pragma unroll
        for (int j = 0; j < 2; j++) {
            int ch = tid + j * 512;
            int r = ch >> 4, c = ch & 15;
            int n = n0 + r;
            float4 v0 = make_float4(0.f, 0.f, 0.f, 0.f), v1 = v0;
            if (n < N) {
                v0 = reinterpret_cast<const float4*>(A)[(size_t)n * 32 + c * 2];
                v1 = reinterpret_cast<const float4*>(A)[(size_t)n * 32 + c * 2 + 1];
            }
            unsigned short t8[8] = {bfb(v0.x), bfb(v0.y), bfb(v0.z), bfb(v0.w),
                                    bfb(v1.x), bfb(v1.y), bfb(v1.z), bfb(v1.w)};
            *reinterpret_cast<uint4*>(&AsB[r * LDA + c * 8]) =
                *reinterpret_cast<uint4*>(t8);
        }
    }
    __syncthreads();

    // 8 waves: wave w -> rows (w&3)*16, col-tiles (w>>2)*4 .. +3
    int lane = tid & 63, wv = tid >> 6;
    int wr = wv & 3, wc = wv >> 2;
    int lrow = lane & 15, lk = lane >> 4;
    f32x4 acc[4];
    #pragma unroll
    for (int ct = 0; ct < 4; ct++) acc[ct] = (f32x4){0.f, 0.f, 0.f, 0.f};
    int arow = wr * 16 + lrow;
    #pragma unroll
    for (int ks = 0; ks < 4; ks++) {
        bf16x8 af = *reinterpret_cast<const bf16x8*>(
            &AsB[arow * LDA + ks * 32 + lk * 8]);
        #pragma unroll
        for (int ct = 0; ct < 4; ct++) {
            bf16x8 bfr = *reinterpret_cast<const bf16x8*>(
                &WtB[((wc * 4 + ct) * 16 + lrow) * LDA + ks * 32 + lk * 8]);
            acc[ct] = __builtin_amdgcn_mfma_f32_16x16x32_bf16(af, bfr, acc[ct], 0, 0, 0);
        }
    }
    __syncthreads();   // all reads of AsB/WtB done; reuse WtB as f32 staging

    float* Ef = reinterpret_cast<float*>(WtB);
    #pragma unroll
    for (int ct = 0; ct < 4; ct++)
        #pragma unroll
        for (int j = 0; j < 4; j++)
            Ef[(wr * 16 + lk * 4 + j) * LDE + (wc * 4 + ct) * 16 + lrow] = acc[ct][j];
    __syncthreads();

    // epilogue: 512 threads, each handles 2 rows x 8 cols
    int tx = tid & 15, ty = tid >> 4;
    int c0 = tx * 8, r0 = ty * 2;
    float o[2][8];
    #pragma unroll
    for (int r = 0; r < 2; r++) {
        float4 v0 = *reinterpret_cast<const float4*>(&Ef[(r0 + r) * LDE + c0]);
        float4 v1 = *reinterpret_cast<const float4*>(&Ef[(r0 + r) * LDE + c0 + 4]);
        o[r][0] = v0.x; o[r][1] = v0.y; o[r][2] = v0.z; o[r][3] = v0.w;
        o[r][4] = v1.x; o[r][5] = v1.y; o[r][6] = v1.z; o[r][7] = v1.w;
    }

    if (MODE == 2) {
        float b[8];
        #pragma unroll
        for (int c = 0; c < 8; c++) b[c] = bias[c0 + c];
        #pragma unroll
        for (int r = 0; r < 2; r++) {
            int n = n0 + r0 + r;
            if (n >= N) continue;
            float4 o0 = make_float4(o[r][0] + b[0], o[r][1] + b[1],
                                    o[r][2] + b[2], o[r][3] + b[3]);
            float4 o1 = make_float4(o[r][4] + b[4], o[r][5] + b[5],
                                    o[r][6] + b[6], o[r][7] + b[7]);
            reinterpret_cast<float4*>(C)[(size_t)n * 32 + tx * 2] = o0;
            reinterpret_cast<float4*>(C)[(size_t)n * 32 + tx * 2 + 1] = o1;
        }
    } else {
        float ats[8], atd[8];
        #pragma unroll
        for (int c = 0; c < 8; c++) { ats[c] = att_s[c0 + c]; atd[c] = att_d[c0 + c]; }
        #pragma unroll
        for (int r = 0; r < 2; r++) {
            int n = n0 + r0 + r;
            union { uint4 v; unsigned short s[8]; } pk;
            #pragma unroll
            for (int c = 0; c < 8; c++) pk.s[c] = bfb(o[r][c]);
            float ps = 0.f, pd = 0.f;
            #pragma unroll
            for (int c = 0; c < 8; c++) { ps += o[r][c] * ats[c]; pd += o[r][c] * atd[c]; }
            ps += __shfl_xor(ps, 1); ps += __shfl_xor(ps, 2);
            pd += __shfl_xor(pd, 1); pd += __shfl_xor(pd, 2);
            if (n < N) {
                *reinterpret_cast<uint4*>(xhb + (size_t)n * D + c0) = pk.v;
                if ((tx & 3) == 0) {
                    a_s[n * H + (tx >> 2)] = ps;
                    a_d[n * H + (tx >> 2)] = pd;
                }
            }
        }
    }
}

// ---------- fused GAT aggregate + bias + LN (+ReLU) + residual ----------
// One wave per node, 8 nodes per 512-thread block (fewer blocks -> less
// dispatch ramp; per-wave structure identical to the 256-thr version).
// SINGLE PASS: no segment-max (lrelu-bounded logits -> exp safe), no LDS.
__global__ __launch_bounds__(512) void k_gat5(
        const __hip_bfloat16* __restrict__ xhb, const int* __restrict__ off,
        const int2* __restrict__ adj2, const float* __restrict__ a_s,
        const float* __restrict__ a_d, const float* __restrict__ bias,
        const float* __restrict__ g, const float* __restrict__ bln,
        float* __restrict__ h, int N, int do_relu) {
    int wid = threadIdx.x >> 6;
    int lane = threadIdx.x & 63;
    int n = blockIdx.x * 8 + wid;
    if (n >= N) return;

    int cl = lane & 15;             // channel group: c0 = 8*cl
    int sub = lane >> 4;            // edge sub-slot (4 edges in flight)
    int hb = cl >> 2;               // head of this lane's channels
    int c0 = cl * 8;

    int beg = off[n], end = off[n + 1];
    int deg = end - beg;
    int items = deg + 1;            // + self loop
    int itp = (items + 3) & ~3;

    float adA = a_d[n * H + hb];
    float den = 0.f;
    float acc[8];
    #pragma unroll
    for (int c = 0; c < 8; c++) acc[c] = 0.f;

    #pragma unroll 4
    for (int pp = sub; pp < itp; pp += 4) {
        int s = (pp < deg) ? adj2[beg + pp].x : n;
        float av = a_s[(size_t)s * H + hb];
        uint4 u = *reinterpret_cast<const uint4*>(xhb + (size_t)s * D + c0);
        float e = lrelu(av + adA);
        float wv = (pp < items) ? __expf(e) : 0.f;
        den += wv;
        float f;
        f = __uint_as_float(u.x << 16);         acc[0] += wv * f;
        f = __uint_as_float(u.x & 0xffff0000u); acc[1] += wv * f;
        f = __uint_as_float(u.y << 16);         acc[2] += wv * f;
        f = __uint_as_float(u.y & 0xffff0000u); acc[3] += wv * f;
        f = __uint_as_float(u.z << 16);         acc[4] += wv * f;
        f = __uint_as_float(u.z & 0xffff0000u); acc[5] += wv * f;
        f = __uint_as_float(u.w << 16);         acc[6] += wv * f;
        f = __uint_as_float(u.w & 0xffff0000u); acc[7] += wv * f;
    }

    #pragma unroll
    for (int c = 0; c < 8; c++) {
        acc[c] += __shfl_xor(acc[c], 16);
        acc[c] += __shfl_xor(acc[c], 32);
    }
    den += __shfl_xor(den, 16);
    den += __shfl_xor(den, 32);
    float rden = 1.0f / den;

    float4 b0 = *reinterpret_cast<const float4*>(bias + c0);
    float4 b1 = *reinterpret_cast<const float4*>(bias + c0 + 4);
    float o[8];
    o[0] = acc[0] * rden + b0.x; o[1] = acc[1] * rden + b0.y;
    o[2] = acc[2] * rden + b0.z; o[3] = acc[3] * rden + b0.w;
    o[4] = acc[4] * rden + b1.x; o[5] = acc[5] * rden + b1.y;
    o[6] = acc[6] * rden + b1.z; o[7] = acc[7] * rden + b1.w;

    float s1 = 0.f;
    #pragma unroll
    for (int c = 0; c < 8; c++) s1 += o[c];
    #pragma unroll
    for (int os = 1; os < 64; os <<= 1) s1 += __shfl_xor(s1, os);
    float mu = s1 * (1.0f / 512.0f);
    float s2 = 0.f;
    #pragma unroll
    for (int c = 0; c < 8; c++) { float dv = o[c] - mu; s2 += dv * dv; }
    #pragma unroll
    for (int os = 1; os < 64; os <<= 1) s2 += __shfl_xor(s2, os);
    float inv = rsqrtf(s2 * (1.0f / 512.0f) + LN_EPS);

    if (sub == 0) {
        float4 g0 = *reinterpret_cast<const float4*>(g + c0);
        float4 g1 = *reinterpret_cast<const float4*>(g + c0 + 4);
        float4 l0 = *reinterpret_cast<const float4*>(bln + c0);
        float4 l1 = *reinterpret_cast<const float4*>(bln + c0 + 4);
        float y[8];
        y[0] = (o[0] - mu) * inv * g0.x + l0.x;
        y[1] = (o[1] - mu) * inv * g0.y + l0.y;
        y[2] = (o[2] - mu) * inv * g0.z + l0.z;
        y[3] = (o[3] - mu) * inv * g0.w + l0.w;
        y[4] = (o[4] - mu) * inv * g1.x + l1.x;
        y[5] = (o[5] - mu) * inv * g1.y + l1.y;
        y[6] = (o[6] - mu) * inv * g1.z + l1.z;
        y[7] = (o[7] - mu) * inv * g1.w + l1.w;
        if (do_relu) {
            #pragma unroll
            for (int c = 0; c < 8; c++) y[c] = fmaxf(y[c], 0.f);
        }
        float4 h0 = *reinterpret_cast<float4*>(h + (size_t)n * D + c0);
        float4 h1 = *reinterpret_cast<float4*>(h + (size_t)n * D + c0 + 4);
        h0.x += y[0]; h0.y += y[1]; h0.z += y[2]; h0.w += y[3];
        h1.x += y[4]; h1.y += y[5]; h1.z += y[6]; h1.w += y[7];
        *reinterpret_cast<float4*>(h + (size_t)n * D + c0) = h0;
        *reinterpret_cast<float4*>(h + (size_t)n * D + c0 + 4) = h1;
    }
}

extern "C" void kernel_launch(void* const* d_in, const int* in_sizes, int n_in,
                              void* d_out, int out_size, void* d_ws, size_t ws_size,
                              hipStream_t stream) {
    const float* x       = (const float*)d_in[0];
    const int*   ei      = (const int*)  d_in[1];
    const float* W_edge  = (const float*)d_in[2];
    const float* b_edge  = (const float*)d_in[3];
    const float* W_node  = (const float*)d_in[4];
    const float* b_node  = (const float*)d_in[5];
    const float* lin_w   = (const float*)d_in[6];
    const float* att_src = (const float*)d_in[7];
    const float* att_dst = (const float*)d_in[8];
    const float* gat_b   = (const float*)d_in[9];
    const float* ln_g    = (const float*)d_in[10];
    const float* ln_b    = (const float*)d_in[11];

    int N = out_size / D;
    int E = in_sizes[1] / 2;
    int NB = (N + 255) / 256;

    char* w = (char*)d_ws;
    auto carve = [&](size_t bytes) {
        void* p = (void*)w;
        w += (bytes + 255) & ~(size_t)255;
        return p;
    };
    int*   cnt  = (int*)  carve((size_t)N * 4);
    int*   off  = (int*)  carve((size_t)(N + 1) * 4);
    int*   rank = (int*)  carve((size_t)E * 4);
    int2*  adj2 = (int2*) carve((size_t)E * 8);
    int*   bsum = (int*)  carve((size_t)NB * 4);
    float* tmp  = (float*)carve((size_t)N * D * 4);
    float* a_s  = (float*)carve((size_t)N * H * 4);
    float* a_d  = (float*)carve((size_t)N * H * 4);
    unsigned short* Wt = (unsigned short*)carve((size_t)4 * D * D * 2);
    __hip_bfloat16* xhb = (__hip_bfloat16*)tmp;

    float* h = (float*)d_out;

    hipMemsetAsync(cnt, 0, (size_t)N * 4, stream);

    int tb = 256;
    k_wprep<<<16, 256, 0, stream>>>(W_node, lin_w, Wt);
    k_rank<<<(E + tb - 1) / tb, tb, 0, stream>>>(ei, cnt, rank, E);
    k_scan_part<<<NB, 256, 0, stream>>>(cnt, off, bsum, N);
    k_scan_top<<<1, 256, 0, stream>>>(bsum, off, NB, N);
    k_scan_add<<<NB, 256, 0, stream>>>(cnt, off, bsum, N);
    k_fill<<<(E + tb - 1) / tb, tb, 0, stream>>>(ei, off, rank, adj2, E);
    k_gemm<2><<<(N + 63) / 64, 512, 0, stream>>>(
        nullptr, Wt, b_node, h, nullptr, nullptr, nullptr, nullptr, nullptr,
        x, adj2, off, W_edge, b_edge, N);

    for (int i = 0; i < 3; i++) {
        k_gemm<1><<<(N + 63) / 64, 512, 0, stream>>>(
            h, Wt + (size_t)(i + 1) * D * D, nullptr, nullptr,
            xhb, a_s, a_d, att_src + i * D, att_dst + i * D,
            nullptr, nullptr, nullptr, nullptr, nullptr, N);
        k_gat5<<<(N + 7) / 8, 512, 0, stream>>>(
            xhb, off, adj2, a_s, a_d,
            gat_b + i * D, ln_g + i * D, ln_b + i * D,
            h, N, (i < 2) ? 1 : 0);
    }
}

// Round 17
// 230.033 us; speedup vs baseline: 1.0457x; 1.0344x over previous
//
#include <hip/hip_runtime.h>
#include <hip/hip_bf16.h>
#include <math.h>

#define D 128
#define H 4
#define NEG_SLOPE 0.2f
#define LN_EPS 1e-5f
#define LDA 136    // bf16 elems per LDS row: 272 B = 17*16B -> conflict-free b128
#define LDE 132    // f32 epilogue LDS row stride

using bf16x8 = __attribute__((ext_vector_type(8))) short;
using f32x4  = __attribute__((ext_vector_type(4))) float;
using f32x2  = __attribute__((ext_vector_type(2))) float;

__device__ __forceinline__ float lrelu(float v) {
    return v > 0.f ? v : NEG_SLOPE * v;
}
__device__ __forceinline__ unsigned short bfb(float f) {
    __hip_bfloat16 h = __float2bfloat16(f);
    return *reinterpret_cast<unsigned short*>(&h);
}

// ---------- histogram + per-edge rank: rank[e] = old count of dst ----------
__global__ void k_rank(const int* __restrict__ ei, int* __restrict__ cnt,
                       int* __restrict__ rank, int E) {
    int e = blockIdx.x * blockDim.x + threadIdx.x;
    if (e >= E) return;
    rank[e] = atomicAdd(&cnt[ei[E + e]], 1);
}

// ---------- hierarchical exclusive scan of cnt[N] -> off[N+1] ----------
__global__ void k_scan_part(const int* __restrict__ cnt, int* __restrict__ off,
                            int* __restrict__ bsum, int N) {
    __shared__ int sm[256];
    int i = blockIdx.x * 256 + threadIdx.x;
    int v = (i < N) ? cnt[i] : 0;
    sm[threadIdx.x] = v;
    __syncthreads();
    #pragma unroll
    for (int o = 1; o < 256; o <<= 1) {
        int t = (threadIdx.x >= (unsigned)o) ? sm[threadIdx.x - o] : 0;
        __syncthreads();
        sm[threadIdx.x] += t;
        __syncthreads();
    }
    if (i < N) off[i] = sm[threadIdx.x];
    if (threadIdx.x == 255) bsum[blockIdx.x] = sm[255];
}

__global__ void k_scan_top(int* __restrict__ bsum, int* __restrict__ off,
                           int NB, int N) {
    __shared__ int sm[256];
    int v = (threadIdx.x < (unsigned)NB) ? bsum[threadIdx.x] : 0;
    sm[threadIdx.x] = v;
    __syncthreads();
    #pragma unroll
    for (int o = 1; o < 256; o <<= 1) {
        int t = (threadIdx.x >= (unsigned)o) ? sm[threadIdx.x - o] : 0;
        __syncthreads();
        sm[threadIdx.x] += t;
        __syncthreads();
    }
    if (threadIdx.x < (unsigned)NB) bsum[threadIdx.x] = sm[threadIdx.x] - v;
    if (threadIdx.x == 255) off[N] = sm[255];
}

__global__ void k_scan_add(const int* __restrict__ cnt, int* __restrict__ off,
                           const int* __restrict__ bsum, int N) {
    int i = blockIdx.x * 256 + threadIdx.x;
    if (i < N) off[i] = off[i] - cnt[i] + bsum[blockIdx.x];
}

// ---------- CSR fill, ATOMIC-FREE: slot = off[dst] + rank[e] ----------
__global__ void k_fill(const int* __restrict__ ei, const int* __restrict__ off,
                       const int* __restrict__ rank, int2* __restrict__ adj2, int E) {
    int e = blockIdx.x * blockDim.x + threadIdx.x;
    if (e >= E) return;
    int dst = ei[E + e];
    int slot = off[dst] + rank[e];
    adj2[slot] = make_int2(ei[e], e);
}

// ---------- weight prep: Wt[w][n][k] = bf16(W_w[k][n]) (transposed) ----------
__global__ __launch_bounds__(256) void k_wprep(
        const float* __restrict__ Wn, const float* __restrict__ lw,
        unsigned short* __restrict__ Wt) {
    __shared__ float Wf[32][132];
    int b = blockIdx.x, w = b >> 2, p = b & 3;
    const float* src = (w == 0) ? (Wn + (size_t)p * 32 * D)
                                : (lw + (size_t)(w - 1) * D * D + (size_t)p * 32 * D);
    int tid = threadIdx.x;
    #pragma unroll
    for (int j = 0; j < 4; j++) {
        int i = tid + j * 256;
        int r = i >> 5, q = i & 31;
        float4 v = reinterpret_cast<const float4*>(src)[i];
        *reinterpret_cast<float4*>(&Wf[r][q * 4]) = v;
    }
    __syncthreads();
    int n = tid & 127, ks = (tid >> 7) * 16;
    unsigned short t16[16];
    #pragma unroll
    for (int j = 0; j < 16; j++) t16[j] = bfb(Wf[ks + j][n]);
    unsigned short* dst = Wt + ((size_t)w * D + n) * D + p * 32 + ks;
    *reinterpret_cast<uint4*>(dst) = *reinterpret_cast<uint4*>(t16);
    *reinterpret_cast<uint4*>(dst + 8) = *reinterpret_cast<uint4*>(t16 + 8);
}

// ---------- MFMA GEMM: C[N,128] = bf16(A[N,128]) @ bf16(W[128,128]) ----------
// 64 rows/block, 512 threads = 8 waves: wave w -> rows (w&3)*16, col-tiles
// (w>>2)*4..+3.
// MODE 1: A explicit (h), bf16 out + fused attention dots.
// MODE 2: A synthesized from scatter-mean, f32 out + bias.
template <int MODE>
__global__ __launch_bounds__(512) void k_gemm(
        const float* __restrict__ A, const unsigned short* __restrict__ Wt,
        const float* __restrict__ bias, float* __restrict__ C,
        __hip_bfloat16* __restrict__ xhb, float* __restrict__ a_s,
        float* __restrict__ a_d, const float* __restrict__ att_s,
        const float* __restrict__ att_d,
        const float* __restrict__ x, const int2* __restrict__ adj2,
        const int* __restrict__ off,
        const float* __restrict__ W_edge, const float* __restrict__ b_edge,
        int N) {
    __shared__ __align__(16) unsigned short AsB[64 * LDA];   // 17.4 KB
    __shared__ __align__(16) unsigned short WtB[128 * LDA];  // 34.8 KB (f32 [64][LDE] in epilogue)
    int tid = threadIdx.x;
    int n0 = blockIdx.x * 64;

    // stage Wt (pre-transposed bf16 [128][128]) -> LDS [128][LDA]
    #pragma unroll
    for (int j = 0; j < 4; j++) {
        int ch = tid + j * 512;
        int r = ch >> 4, c = ch & 15;
        uint4 v = *reinterpret_cast<const uint4*>(Wt + (size_t)r * D + c * 8);
        *reinterpret_cast<uint4*>(&WtB[r * LDA + c * 8]) = v;
    }

    if (MODE == 2) {
        __shared__ float rowf[64][4];
        {
            int r = tid >> 3, t8v = tid & 7;
            int n = n0 + r;
            float s0 = 0.f, s1 = 0.f, s2 = 0.f;
            int degv = 0;
            if (n < N) {
                int beg = off[n], end = off[n + 1];
                degv = end - beg;
                for (int p = beg + t8v; p < end; p += 8) {
                    const float* xr = x + (size_t)adj2[p].y * 3;
                    s0 += xr[0]; s1 += xr[1]; s2 += xr[2];
                }
            }
            #pragma unroll
            for (int o = 1; o < 8; o <<= 1) {
                s0 += __shfl_xor(s0, o);
                s1 += __shfl_xor(s1, o);
                s2 += __shfl_xor(s2, o);
            }
            if (t8v == 0)
                *reinterpret_cast<float4*>(rowf[r]) =
                    make_float4(s0, s1, s2, (float)degv);
        }
        __syncthreads();
        #pragma unroll
        for (int j = 0; j < 2; j++) {
            int ch = tid + j * 512;
            int r = ch >> 4, c = ch & 15;
            float4 rv = *reinterpret_cast<float4*>(rowf[r]);
            float cn = rv.w, rc = 1.f / fmaxf(cn, 1.f);
            int d0 = c * 8;
            unsigned short t8[8];
            #pragma unroll
            for (int q = 0; q < 2; q++) {
                float4 we0 = *reinterpret_cast<const float4*>(W_edge + d0 + q * 4);
                float4 we1 = *reinterpret_cast<const float4*>(W_edge + D + d0 + q * 4);
                float4 we2 = *reinterpret_cast<const float4*>(W_edge + 2 * D + d0 + q * 4);
                float4 be  = *reinterpret_cast<const float4*>(b_edge + d0 + q * 4);
                t8[q * 4 + 0] = bfb((rv.x * we0.x + rv.y * we1.x + rv.z * we2.x + cn * be.x) * rc);
                t8[q * 4 + 1] = bfb((rv.x * we0.y + rv.y * we1.y + rv.z * we2.y + cn * be.y) * rc);
                t8[q * 4 + 2] = bfb((rv.x * we0.z + rv.y * we1.z + rv.z * we2.z + cn * be.z) * rc);
                t8[q * 4 + 3] = bfb((rv.x * we0.w + rv.y * we1.w + rv.z * we2.w + cn * be.w) * rc);
            }
            *reinterpret_cast<uint4*>(&AsB[r * LDA + c * 8]) =
                *reinterpret_cast<uint4*>(t8);
        }
    } else {
        #pragma unroll
        for (int j = 0; j < 2; j++) {
            int ch = tid + j * 512;
            int r = ch >> 4, c = ch & 15;
            int n = n0 + r;
            float4 v0 = make_float4(0.f, 0.f, 0.f, 0.f), v1 = v0;
            if (n < N) {
                v0 = reinterpret_cast<const float4*>(A)[(size_t)n * 32 + c * 2];
                v1 = reinterpret_cast<const float4*>(A)[(size_t)n * 32 + c * 2 + 1];
            }
            unsigned short t8[8] = {bfb(v0.x), bfb(v0.y), bfb(v0.z), bfb(v0.w),
                                    bfb(v1.x), bfb(v1.y), bfb(v1.z), bfb(v1.w)};
            *reinterpret_cast<uint4*>(&AsB[r * LDA + c * 8]) =
                *reinterpret_cast<uint4*>(t8);
        }
    }
    __syncthreads();

    // 8 waves: wave w -> rows (w&3)*16, col-tiles (w>>2)*4 .. +3
    int lane = tid & 63, wv = tid >> 6;
    int wr = wv & 3, wc = wv >> 2;
    int lrow = lane & 15, lk = lane >> 4;
    f32x4 acc[4];
    #pragma unroll
    for (int ct = 0; ct < 4; ct++) acc[ct] = (f32x4){0.f, 0.f, 0.f, 0.f};
    int arow = wr * 16 + lrow;
    #pragma unroll
    for (int ks = 0; ks < 4; ks++) {
        bf16x8 af = *reinterpret_cast<const bf16x8*>(
            &AsB[arow * LDA + ks * 32 + lk * 8]);
        #pragma unroll
        for (int ct = 0; ct < 4; ct++) {
            bf16x8 bfr = *reinterpret_cast<const bf16x8*>(
                &WtB[((wc * 4 + ct) * 16 + lrow) * LDA + ks * 32 + lk * 8]);
            acc[ct] = __builtin_amdgcn_mfma_f32_16x16x32_bf16(af, bfr, acc[ct], 0, 0, 0);
        }
    }
    __syncthreads();   // all reads of AsB/WtB done; reuse WtB as f32 staging

    float* Ef = reinterpret_cast<float*>(WtB);
    #pragma unroll
    for (int ct = 0; ct < 4; ct++)
        #pragma unroll
        for (int j = 0; j < 4; j++)
            Ef[(wr * 16 + lk * 4 + j) * LDE + (wc * 4 + ct) * 16 + lrow] = acc[ct][j];
    __syncthreads();

    // epilogue: 512 threads, each handles 2 rows x 8 cols
    int tx = tid & 15, ty = tid >> 4;
    int c0 = tx * 8, r0 = ty * 2;
    float o[2][8];
    #pragma unroll
    for (int r = 0; r < 2; r++) {
        float4 v0 = *reinterpret_cast<const float4*>(&Ef[(r0 + r) * LDE + c0]);
        float4 v1 = *reinterpret_cast<const float4*>(&Ef[(r0 + r) * LDE + c0 + 4]);
        o[r][0] = v0.x; o[r][1] = v0.y; o[r][2] = v0.z; o[r][3] = v0.w;
        o[r][4] = v1.x; o[r][5] = v1.y; o[r][6] = v1.z; o[r][7] = v1.w;
    }

    if (MODE == 2) {
        float b[8];
        #pragma unroll
        for (int c = 0; c < 8; c++) b[c] = bias[c0 + c];
        #pragma unroll
        for (int r = 0; r < 2; r++) {
            int n = n0 + r0 + r;
            if (n >= N) continue;
            float4 o0 = make_float4(o[r][0] + b[0], o[r][1] + b[1],
                                    o[r][2] + b[2], o[r][3] + b[3]);
            float4 o1 = make_float4(o[r][4] + b[4], o[r][5] + b[5],
                                    o[r][6] + b[6], o[r][7] + b[7]);
            reinterpret_cast<float4*>(C)[(size_t)n * 32 + tx * 2] = o0;
            reinterpret_cast<float4*>(C)[(size_t)n * 32 + tx * 2 + 1] = o1;
        }
    } else {
        float ats[8], atd[8];
        #pragma unroll
        for (int c = 0; c < 8; c++) { ats[c] = att_s[c0 + c]; atd[c] = att_d[c0 + c]; }
        #pragma unroll
        for (int r = 0; r < 2; r++) {
            int n = n0 + r0 + r;
            union { uint4 v; unsigned short s[8]; } pk;
            #pragma unroll
            for (int c = 0; c < 8; c++) pk.s[c] = bfb(o[r][c]);
            float ps = 0.f, pd = 0.f;
            #pragma unroll
            for (int c = 0; c < 8; c++) { ps += o[r][c] * ats[c]; pd += o[r][c] * atd[c]; }
            ps += __shfl_xor(ps, 1); ps += __shfl_xor(ps, 2);
            pd += __shfl_xor(pd, 1); pd += __shfl_xor(pd, 2);
            if (n < N) {
                *reinterpret_cast<uint4*>(xhb + (size_t)n * D + c0) = pk.v;
                if ((tx & 3) == 0) {
                    a_s[n * H + (tx >> 2)] = ps;
                    a_d[n * H + (tx >> 2)] = pd;
                }
            }
        }
    }
}

// ---------- fused GAT aggregate + bias + LN (+ReLU) + residual ----------
// One wave per node, 4 nodes per 256-thread block (R14 config). SINGLE PASS:
// no segment-max, no LDS. Accumulators are <2 x float> vectors so the
// backend can select v_pk_fma_f32 (dual f32 FMA) in the gather loop.
__global__ __launch_bounds__(256) void k_gat5(
        const __hip_bfloat16* __restrict__ xhb, const int* __restrict__ off,
        const int2* __restrict__ adj2, const float* __restrict__ a_s,
        const float* __restrict__ a_d, const float* __restrict__ bias,
        const float* __restrict__ g, const float* __restrict__ bln,
        float* __restrict__ h, int N, int do_relu) {
    int wid = threadIdx.x >> 6;
    int lane = threadIdx.x & 63;
    int n = blockIdx.x * 4 + wid;
    if (n >= N) return;

    int cl = lane & 15;             // channel group: c0 = 8*cl
    int sub = lane >> 4;            // edge sub-slot (4 edges in flight)
    int hb = cl >> 2;               // head of this lane's channels
    int c0 = cl * 8;

    int beg = off[n], end = off[n + 1];
    int deg = end - beg;
    int items = deg + 1;            // + self loop
    int itp = (items + 3) & ~3;

    float adA = a_d[n * H + hb];
    float den = 0.f;
    f32x2 acc2[4];
    #pragma unroll
    for (int c = 0; c < 4; c++) acc2[c] = (f32x2){0.f, 0.f};

    #pragma unroll 4
    for (int pp = sub; pp < itp; pp += 4) {
        int s = (pp < deg) ? adj2[beg + pp].x : n;
        float av = a_s[(size_t)s * H + hb];
        uint4 u = *reinterpret_cast<const uint4*>(xhb + (size_t)s * D + c0);
        float e = lrelu(av + adA);
        float wv = (pp < items) ? __expf(e) : 0.f;
        den += wv;
        f32x2 wv2 = (f32x2){wv, wv};
        f32x2 f;
        f = (f32x2){__uint_as_float(u.x << 16), __uint_as_float(u.x & 0xffff0000u)};
        acc2[0] += wv2 * f;
        f = (f32x2){__uint_as_float(u.y << 16), __uint_as_float(u.y & 0xffff0000u)};
        acc2[1] += wv2 * f;
        f = (f32x2){__uint_as_float(u.z << 16), __uint_as_float(u.z & 0xffff0000u)};
        acc2[2] += wv2 * f;
        f = (f32x2){__uint_as_float(u.w << 16), __uint_as_float(u.w & 0xffff0000u)};
        acc2[3] += wv2 * f;
    }

    float acc[8];
    #pragma unroll
    for (int c = 0; c < 4; c++) { acc[2 * c] = acc2[c].x; acc[2 * c + 1] = acc2[c].y; }

    #pragma unroll
    for (int c = 0; c < 8; c++) {
        acc[c] += __shfl_xor(acc[c], 16);
        acc[c] += __shfl_xor(acc[c], 32);
    }
    den += __shfl_xor(den, 16);
    den += __shfl_xor(den, 32);
    float rden = 1.0f / den;

    float4 b0 = *reinterpret_cast<const float4*>(bias + c0);
    float4 b1 = *reinterpret_cast<const float4*>(bias + c0 + 4);
    float o[8];
    o[0] = acc[0] * rden + b0.x; o[1] = acc[1] * rden + b0.y;
    o[2] = acc[2] * rden + b0.z; o[3] = acc[3] * rden + b0.w;
    o[4] = acc[4] * rden + b1.x; o[5] = acc[5] * rden + b1.y;
    o[6] = acc[6] * rden + b1.z; o[7] = acc[7] * rden + b1.w;

    float s1 = 0.f;
    #pragma unroll
    for (int c = 0; c < 8; c++) s1 += o[c];
    #pragma unroll
    for (int os = 1; os < 64; os <<= 1) s1 += __shfl_xor(s1, os);
    float mu = s1 * (1.0f / 512.0f);
    float s2 = 0.f;
    #pragma unroll
    for (int c = 0; c < 8; c++) { float dv = o[c] - mu; s2 += dv * dv; }
    #pragma unroll
    for (int os = 1; os < 64; os <<= 1) s2 += __shfl_xor(s2, os);
    float inv = rsqrtf(s2 * (1.0f / 512.0f) + LN_EPS);

    if (sub == 0) {
        float4 g0 = *reinterpret_cast<const float4*>(g + c0);
        float4 g1 = *reinterpret_cast<const float4*>(g + c0 + 4);
        float4 l0 = *reinterpret_cast<const float4*>(bln + c0);
        float4 l1 = *reinterpret_cast<const float4*>(bln + c0 + 4);
        float y[8];
        y[0] = (o[0] - mu) * inv * g0.x + l0.x;
        y[1] = (o[1] - mu) * inv * g0.y + l0.y;
        y[2] = (o[2] - mu) * inv * g0.z + l0.z;
        y[3] = (o[3] - mu) * inv * g0.w + l0.w;
        y[4] = (o[4] - mu) * inv * g1.x + l1.x;
        y[5] = (o[5] - mu) * inv * g1.y + l1.y;
        y[6] = (o[6] - mu) * inv * g1.z + l1.z;
        y[7] = (o[7] - mu) * inv * g1.w + l1.w;
        if (do_relu) {
            #pragma unroll
            for (int c = 0; c < 8; c++) y[c] = fmaxf(y[c], 0.f);
        }
        float4 h0 = *reinterpret_cast<float4*>(h + (size_t)n * D + c0);
        float4 h1 = *reinterpret_cast<float4*>(h + (size_t)n * D + c0 + 4);
        h0.x += y[0]; h0.y += y[1]; h0.z += y[2]; h0.w += y[3];
        h1.x += y[4]; h1.y += y[5]; h1.z += y[6]; h1.w += y[7];
        *reinterpret_cast<float4*>(h + (size_t)n * D + c0) = h0;
        *reinterpret_cast<float4*>(h + (size_t)n * D + c0 + 4) = h1;
    }
}

extern "C" void kernel_launch(void* const* d_in, const int* in_sizes, int n_in,
                              void* d_out, int out_size, void* d_ws, size_t ws_size,
                              hipStream_t stream) {
    const float* x       = (const float*)d_in[0];
    const int*   ei      = (const int*)  d_in[1];
    const float* W_edge  = (const float*)d_in[2];
    const float* b_edge  = (const float*)d_in[3];
    const float* W_node  = (const float*)d_in[4];
    const float* b_node  = (const float*)d_in[5];
    const float* lin_w   = (const float*)d_in[6];
    const float* att_src = (const float*)d_in[7];
    const float* att_dst = (const float*)d_in[8];
    const float* gat_b   = (const float*)d_in[9];
    const float* ln_g    = (const float*)d_in[10];
    const float* ln_b    = (const float*)d_in[11];

    int N = out_size / D;
    int E = in_sizes[1] / 2;
    int NB = (N + 255) / 256;

    char* w = (char*)d_ws;
    auto carve = [&](size_t bytes) {
        void* p = (void*)w;
        w += (bytes + 255) & ~(size_t)255;
        return p;
    };
    int*   cnt  = (int*)  carve((size_t)N * 4);
    int*   off  = (int*)  carve((size_t)(N + 1) * 4);
    int*   rank = (int*)  carve((size_t)E * 4);
    int2*  adj2 = (int2*) carve((size_t)E * 8);
    int*   bsum = (int*)  carve((size_t)NB * 4);
    float* tmp  = (float*)carve((size_t)N * D * 4);
    float* a_s  = (float*)carve((size_t)N * H * 4);
    float* a_d  = (float*)carve((size_t)N * H * 4);
    unsigned short* Wt = (unsigned short*)carve((size_t)4 * D * D * 2);
    __hip_bfloat16* xhb = (__hip_bfloat16*)tmp;

    float* h = (float*)d_out;

    hipMemsetAsync(cnt, 0, (size_t)N * 4, stream);

    int tb = 256;
    k_wprep<<<16, 256, 0, stream>>>(W_node, lin_w, Wt);
    k_rank<<<(E + tb - 1) / tb, tb, 0, stream>>>(ei, cnt, rank, E);
    k_scan_part<<<NB, 256, 0, stream>>>(cnt, off, bsum, N);
    k_scan_top<<<1, 256, 0, stream>>>(bsum, off, NB, N);
    k_scan_add<<<NB, 256, 0, stream>>>(cnt, off, bsum, N);
    k_fill<<<(E + tb - 1) / tb, tb, 0, stream>>>(ei, off, rank, adj2, E);
    k_gemm<2><<<(N + 63) / 64, 512, 0, stream>>>(
        nullptr, Wt, b_node, h, nullptr, nullptr, nullptr, nullptr, nullptr,
        x, adj2, off, W_edge, b_edge, N);

    for (int i = 0; i < 3; i++) {
        k_gemm<1><<<(N + 63) / 64, 512, 0, stream>>>(
            h, Wt + (size_t)(i + 1) * D * D, nullptr, nullptr,
            xhb, a_s, a_d, att_src + i * D, att_dst + i * D,
            nullptr, nullptr, nullptr, nullptr, nullptr, N);
        k_gat5<<<(N + 3) / 4, 256, 0, stream>>>(
            xhb, off, adj2, a_s, a_d,
            gat_b + i * D, ln_g + i * D, ln_b + i * D,
            h, N, (i < 2) ? 1 : 0);
    }
}